// Round 16
// baseline (338.303 us; speedup 1.0000x reference)
//
#include <hip/hip_runtime.h>

static constexpr int NN  = 20000;
static constexpr int NE  = 320000;
static constexpr int NTY = 4;
static constexpr int NRL = 8;
static constexpr int NB  = NRL * NN;   // 160000 bins = (rel, perm-dst)

// prep-kernel segment sizes (blocks of 256)
static constexpr int ZB   = (NB + NN * 4 + 255) / 256;  // 938  (zero bcnt+denom)
static constexpr int CB   = (NN + 255) / 256;           // 79   (type-count blocks)
static constexpr int WSEG = 192;                        // 12 mats x 16 tiles (Wk/Wq/Wv)
static constexpr int ASEG = 64;                         // 4 mats x 16 tiles (Wa)
static constexpr int RSEG = 32;                         // 32 rh, att+msg each

typedef short bf16x8 __attribute__((ext_vector_type(8)));
typedef float f32x4  __attribute__((ext_vector_type(4)));
typedef unsigned short u16x4 __attribute__((ext_vector_type(4)));

__device__ __forceinline__ unsigned short f2bf(float f) {
  unsigned u = __float_as_uint(f);
  u += 0x7fffu + ((u >> 16) & 1u);
  return (unsigned short)(u >> 16);
}
__device__ __forceinline__ float bf2f(unsigned short b) {
  return __uint_as_float(((unsigned)b) << 16);
}
__device__ __forceinline__ f32x4 mfma16(bf16x8 a, bf16x8 b, f32x4 c) {
  return __builtin_amdgcn_mfma_f32_16x16x32_bf16(a, b, c, 0, 0, 0);
}

// ---------------- fused prep: zero + tcount + coalesced tiled transposes -----------
__global__ void k_prep_all(const float* __restrict__ Wk, const float* __restrict__ Wq,
                           const float* __restrict__ Wv, const float* __restrict__ Wa,
                           const float* __restrict__ ratt, const float* __restrict__ rmsg,
                           const int* __restrict__ ntype,
                           int* bcnt, float* denom, int* c4p,
                           unsigned short* Wt, unsigned short* At,
                           unsigned short* Att, unsigned short* Mt) {
  __shared__ float tl[64][65];
  __shared__ int cc[4];
  int b = blockIdx.x, tid = threadIdx.x;
  if (b < ZB) {
    int i = b * 256 + tid;
    if (i < NB) bcnt[i] = 0;
    else if (i < NB + NN * 4) denom[i - NB] = 0.f;
    return;
  }
  b -= ZB;
  if (b < CB) {
    if (tid < 4) cc[tid] = 0;
    __syncthreads();
    int i = b * 256 + tid;
    if (i < NN) atomicAdd(&cc[ntype[i]], 1);
    __syncthreads();
    if (tid < 4) c4p[b * 4 + tid] = cc[tid];
    return;
  }
  b -= CB;
  int r4 = tid >> 6, c = tid & 63;
  if (b < WSEG) {
    int mat = b >> 4, tile = b & 15;
    int t = mat / 3, w = mat % 3;
    const float* src = (w == 0) ? Wk : (w == 1) ? Wq : Wv;
    src += (size_t)t * 65536;
    int ti = (tile >> 2) * 64, tj = (tile & 3) * 64;
#pragma unroll
    for (int p = 0; p < 16; ++p) {
      int row = p * 4 + r4;
      tl[row][c] = src[(size_t)(ti + row) * 256 + tj + c];
    }
    __syncthreads();
#pragma unroll
    for (int p = 0; p < 16; ++p) {
      int jr = p * 4 + r4;
      Wt[((size_t)(t * 768 + w * 256 + tj + jr)) * 256 + ti + c] = f2bf(tl[c][jr]);
    }
    return;
  }
  b -= WSEG;
  if (b < ASEG) {
    int t = b >> 4, tile = b & 15;
    int ti = (tile >> 2) * 64, tj = (tile & 3) * 64;
#pragma unroll
    for (int p = 0; p < 16; ++p) {
      int row = p * 4 + r4;
      tl[row][c] = Wa[(size_t)(t * 256 + ti + row) * 256 + tj + c];
    }
    __syncthreads();
#pragma unroll
    for (int p = 0; p < 16; ++p) {
      int jr = p * 4 + r4;
      At[((size_t)(t * 256 + tj + jr)) * 256 + ti + c] = f2bf(tl[c][jr]);
    }
    return;
  }
  b -= ASEG;
  {
    int rh = b;  // 0..31
#pragma unroll
    for (int p = 0; p < 16; ++p) {
      int d = p * 4 + r4;
      tl[d][c] = ratt[(size_t)rh * 4096 + d * 64 + c];
    }
    __syncthreads();
#pragma unroll
    for (int p = 0; p < 16; ++p) {
      int e = p * 4 + r4;
      Att[(size_t)rh * 4096 + e * 64 + c] = f2bf(tl[c][e]);
    }
    __syncthreads();
#pragma unroll
    for (int p = 0; p < 16; ++p) {
      int d = p * 4 + r4;
      tl[d][c] = rmsg[(size_t)rh * 4096 + d * 64 + c];
    }
    __syncthreads();
#pragma unroll
    for (int p = 0; p < 16; ++p) {
      int e = p * 4 + r4;
      Mt[(size_t)rh * 4096 + e * 64 + c] = f2bf(tl[c][e]);
    }
  }
}

// meta: type offsets + 64-row tile list
__global__ void k_meta(const int* __restrict__ c4p, int* toff, int* ncur,
                       int* mt64_t, int* mt64_m, int* gcnt) {
  __shared__ int c4[4];
  __shared__ int ts[5];
  if (threadIdx.x < 4) {
    int s = 0;
    for (int b = 0; b < CB; ++b) s += c4p[b * 4 + threadIdx.x];
    c4[threadIdx.x] = s;
  }
  __syncthreads();
  if (threadIdx.x == 0) {
    int s = 0, s2 = 0;
    for (int t = 0; t < NTY; ++t) {
      toff[t] = s; ncur[t] = s; s += c4[t];
      ts[t] = s2; s2 += (c4[t] + 63) >> 6;
    }
    toff[NTY] = s; ts[NTY] = s2; gcnt[0] = s2;
  }
  __syncthreads();
  int n64 = ts[4];
  for (int i = threadIdx.x; i < n64; i += 256) {
    int t = 0;
    while (t < 3 && i >= ts[t + 1]) ++t;
    mt64_t[i] = t; mt64_m[i] = i - ts[t];
  }
}
__global__ void k_nscatter(const int* __restrict__ key, int* cur,
                           int* nperm, int* inv) {
  int i = blockIdx.x * 256 + threadIdx.x;
  if (i < NN) {
    int p = atomicAdd(&cur[key[i]], 1);
    nperm[p] = i;
    inv[i] = p;
  }
}

// ---------------- edge CSR by (rel, perm-dst) ----------------
__global__ void k_bcount(const int* __restrict__ etyp, const int* __restrict__ coli,
                         const int* __restrict__ inv, int* bcnt) {
  int e = blockIdx.x * 256 + threadIdx.x;
  if (e < NE) atomicAdd(&bcnt[etyp[e] * NN + inv[coli[e]]], 1);
}
__global__ void k_scan1(const int* cnt, int* off, int* psum) {
  __shared__ int sm[256];
  int i = blockIdx.x * 256 + threadIdx.x;
  int v = cnt[i];
  sm[threadIdx.x] = v;
  __syncthreads();
  for (int d = 1; d < 256; d <<= 1) {
    int t = (threadIdx.x >= d) ? sm[threadIdx.x - d] : 0;
    __syncthreads();
    sm[threadIdx.x] += t;
    __syncthreads();
  }
  off[i] = sm[threadIdx.x] - v;
  if (threadIdx.x == 255) psum[blockIdx.x] = sm[255];
}
__global__ void k_scan2(int* psum) {
  __shared__ int sm[1024];
  int t = threadIdx.x;
  int v = (t < 625) ? psum[t] : 0;
  sm[t] = v;
  __syncthreads();
  for (int d = 1; d < 1024; d <<= 1) {
    int x = (t >= d) ? sm[t - d] : 0;
    __syncthreads();
    sm[t] += x;
    __syncthreads();
  }
  if (t < 625) psum[t] = sm[t] - v;
}
__global__ void k_scan3(int* off, int* cur, const int* psum) {
  int i = blockIdx.x * 256 + threadIdx.x;
  int v = off[i] + psum[blockIdx.x];
  off[i] = v; cur[i] = v;
  if (i == 0) off[NB] = NE;
}
__global__ void k_escatter(const int* __restrict__ etyp, const int* __restrict__ rowi,
                           const int* __restrict__ coli, const int* __restrict__ inv,
                           int* cur, int* je) {
  int e = blockIdx.x * 256 + threadIdx.x;
  if (e >= NE) return;
  int bin = etyp[e] * NN + inv[coli[e]];
  int j = atomicAdd(&cur[bin], 1);
  je[j] = inv[rowi[e]];
}

// ---------------- K1: typed K/Q/V projection, 64-row x 16-col-tile blocks ------------
__global__ __launch_bounds__(256) void k_gemm_kqv(
    const float* __restrict__ hsrc, const unsigned short* __restrict__ Wt,
    const int* __restrict__ nperm, const int* __restrict__ toff,
    const int* __restrict__ mt64_t, const int* __restrict__ mt64_m,
    const int* __restrict__ gcnt,
    unsigned short* __restrict__ kvb, unsigned short* __restrict__ qb) {
  __shared__ unsigned short bs[16][264];
  int mtile = blockIdx.x / 3, chunk = blockIdx.x % 3;
  if (mtile >= gcnt[0]) return;
  int wave = threadIdx.x >> 6, lane = threadIdx.x & 63;
  int t = mt64_t[mtile], tm = mt64_m[mtile];
  int base = toff[t], cnt = toff[t + 1] - base;
  int lr = lane & 15, kq = lane >> 4;
  int arow = tm * 64 + wave * 16 + lr;
  int prow = base + (arow < cnt ? arow : cnt - 1);
  int node = nperm[prow];
  const float* ap = hsrc + (size_t)node * 256 + kq * 8;
  bf16x8 af[8];
#pragma unroll
  for (int s = 0; s < 8; ++s) {
    f32x4 x0 = *(const f32x4*)(ap + s * 32);
    f32x4 x1 = *(const f32x4*)(ap + s * 32 + 4);
    bf16x8 o;
    o[0] = (short)f2bf(x0[0]); o[1] = (short)f2bf(x0[1]);
    o[2] = (short)f2bf(x0[2]); o[3] = (short)f2bf(x0[3]);
    o[4] = (short)f2bf(x1[0]); o[5] = (short)f2bf(x1[1]);
    o[6] = (short)f2bf(x1[2]); o[7] = (short)f2bf(x1[3]);
    af[s] = o;
  }
  int pr[4]; bool wr[4];
#pragma unroll
  for (int i = 0; i < 4; ++i) {
    int crow = tm * 64 + wave * 16 + kq * 4 + i;
    wr[i] = crow < cnt;
    pr[i] = base + (wr[i] ? crow : 0);
  }
  int sc = threadIdx.x >> 4;     // staging col 0..15
  int seg = threadIdx.x & 15;    // staging 16-short segment
  for (int tt = 0; tt < 16; ++tt) {
    int tn = chunk * 16 + tt;
    const unsigned short* wsrc = Wt + ((size_t)(t * 768 + tn * 16 + sc)) * 256 + seg * 16;
    __syncthreads();
    *(bf16x8*)&bs[sc][seg * 16]     = *(const bf16x8*)wsrc;
    *(bf16x8*)&bs[sc][seg * 16 + 8] = *(const bf16x8*)(wsrc + 8);
    __syncthreads();
    f32x4 acc = {0.f, 0.f, 0.f, 0.f};
#pragma unroll
    for (int s = 0; s < 8; ++s)
      acc = mfma16(af[s], *(const bf16x8*)&bs[lr][kq * 8 + s * 32], acc);
    int ccol = tn * 16 + lr;
#pragma unroll
    for (int i = 0; i < 4; ++i) {
      if (wr[i]) {
        unsigned short v = f2bf(acc[i]);
        if (ccol < 256)
          kvb[(size_t)pr[i] * 512 + (ccol >> 6) * 128 + (ccol & 63)] = v;
        else if (ccol < 512)
          qb[(size_t)pr[i] * 256 + (ccol - 256)] = v;
        else {
          int c = ccol - 512;
          kvb[(size_t)pr[i] * 512 + (c >> 6) * 128 + 64 + (c & 63)] = v;
        }
      }
    }
  }
}

// ---------------- K2: mega — 32 bins/wave + XCD swizzle + 2-deep gather pipeline ----
__global__ __launch_bounds__(256) void k_mega(
    const int* __restrict__ boff, const int* __restrict__ je,
    const unsigned short* __restrict__ qb, const unsigned short* __restrict__ kvb,
    const unsigned short* __restrict__ Att, const unsigned short* __restrict__ Mt,
    const float* __restrict__ pri, unsigned short* __restrict__ aggh,
    float* __restrict__ denom) {
  __shared__ float qsh[4][32][68];   // [head][dst_local][dim] f32, stride 68
  int xcd = blockIdx.x & 7, loc = blockIdx.x >> 3;
  int virt = (xcd < 4) ? xcd * 313 + loc : 1252 + (xcd - 4) * 312 + loc;
  int dt = virt >> 2, quarter = virt & 3;
  int h = threadIdx.x >> 6, lane = threadIdx.x & 63;
  int lr16 = lane & 15, kq4 = lane >> 4;    // MFMA mapping
  int lr32 = lane & 31, kq1 = lane >> 5;    // edge-loop mapping
  int r0 = quarter * 2;
  float dtot = 0.f;
  const unsigned short* base_kv = kvb + h * 128 + kq1 * 32;
  f32x4 C[2][4] = {{{0.f,0.f,0.f,0.f},{0.f,0.f,0.f,0.f},{0.f,0.f,0.f,0.f},{0.f,0.f,0.f,0.f}},
                   {{0.f,0.f,0.f,0.f},{0.f,0.f,0.f,0.f},{0.f,0.f,0.f,0.f},{0.f,0.f,0.f,0.f}}};
  for (int rr = 0; rr < 2; ++rr) {
    int r = r0 + rr;
    int rh = r * 4 + h;
    int bin = r * NN + dt * 32 + lr32;
    int b0 = boff[bin], b1 = boff[bin + 1];
    // ---- phase 1: qt = q @ A_r^T via MFMA (two 16-row halves) -> qsh f32 ----
#pragma unroll
    for (int hf = 0; hf < 2; ++hf) {
      const unsigned short* ap = qb + (size_t)(dt * 32 + hf * 16 + lr16) * 256 + h * 64 + kq4 * 8;
      bf16x8 aq0 = *(const bf16x8*)ap;
      bf16x8 aq1 = *(const bf16x8*)(ap + 32);
#pragma unroll
      for (int tn = 0; tn < 4; ++tn) {
        const unsigned short* bp = Att + ((rh * 64 + tn * 16 + lr16) * 64) + kq4 * 8;
        f32x4 a = {0.f, 0.f, 0.f, 0.f};
        a = mfma16(aq0, *(const bf16x8*)bp, a);
        a = mfma16(aq1, *(const bf16x8*)(bp + 32), a);
#pragma unroll
        for (int i = 0; i < 4; ++i)
          qsh[h][hf * 16 + kq4 * 4 + i][tn * 16 + lr16] = a[i];
      }
    }
    // ---- qt -> registers (wave-local LDS round trip) ----
    float qt[32];
#pragma unroll
    for (int m = 0; m < 32; m += 4) {
      f32x4 v = *(const f32x4*)&qsh[h][lr32][kq1 * 32 + m];
      qt[m] = v[0]; qt[m + 1] = v[1]; qt[m + 2] = v[2]; qt[m + 3] = v[3];
    }
    // ---- phase 2: 2-deep software-pipelined per-lane bin walk ----
    float acc[32];
#pragma unroll
    for (int m = 0; m < 32; ++m) acc[m] = 0.f;
    float prs = pri[rh] * 0.125f;
    int n = b1 - b0;
    if (n > 0) {
      int sA = je[b0];
      int sB = (n > 1) ? je[b0 + 1] : sA;
      const unsigned short* pA = base_kv + (size_t)sA * 512;
      const unsigned short* pB = base_kv + (size_t)sB * 512;
      bf16x8 Ak0 = *(const bf16x8*)pA,        Ak1 = *(const bf16x8*)(pA + 8);
      bf16x8 Ak2 = *(const bf16x8*)(pA + 16), Ak3 = *(const bf16x8*)(pA + 24);
      bf16x8 Av0 = *(const bf16x8*)(pA + 64), Av1 = *(const bf16x8*)(pA + 72);
      bf16x8 Av2 = *(const bf16x8*)(pA + 80), Av3 = *(const bf16x8*)(pA + 88);
      bf16x8 Bk0 = *(const bf16x8*)pB,        Bk1 = *(const bf16x8*)(pB + 8);
      bf16x8 Bk2 = *(const bf16x8*)(pB + 16), Bk3 = *(const bf16x8*)(pB + 24);
      bf16x8 Bv0 = *(const bf16x8*)(pB + 64), Bv1 = *(const bf16x8*)(pB + 72);
      bf16x8 Bv2 = *(const bf16x8*)(pB + 80), Bv3 = *(const bf16x8*)(pB + 88);
      for (int jj = 0; jj < n; jj += 2) {
        // consume A (edge jj)
        float s = 0.f;
#pragma unroll
        for (int m = 0; m < 8; ++m) {
          s += qt[m]      * bf2f((unsigned short)Ak0[m]);
          s += qt[8 + m]  * bf2f((unsigned short)Ak1[m]);
          s += qt[16 + m] * bf2f((unsigned short)Ak2[m]);
          s += qt[24 + m] * bf2f((unsigned short)Ak3[m]);
        }
        s += __shfl_xor(s, 32);
        float ex = __expf(s * prs);
        dtot += ex;
#pragma unroll
        for (int m = 0; m < 8; ++m) {
          acc[m]      += ex * bf2f((unsigned short)Av0[m]);
          acc[8 + m]  += ex * bf2f((unsigned short)Av1[m]);
          acc[16 + m] += ex * bf2f((unsigned short)Av2[m]);
          acc[24 + m] += ex * bf2f((unsigned short)Av3[m]);
        }
        // refill A for edge jj+2 (clamped to row 0 past end; never consumed)
        int sA2 = (jj + 2 < n) ? je[b0 + jj + 2] : 0;
        const unsigned short* nA = base_kv + (size_t)sA2 * 512;
        Ak0 = *(const bf16x8*)nA;        Ak1 = *(const bf16x8*)(nA + 8);
        Ak2 = *(const bf16x8*)(nA + 16); Ak3 = *(const bf16x8*)(nA + 24);
        Av0 = *(const bf16x8*)(nA + 64); Av1 = *(const bf16x8*)(nA + 72);
        Av2 = *(const bf16x8*)(nA + 80); Av3 = *(const bf16x8*)(nA + 88);
        // consume B (edge jj+1) — kq1-pair lanes share n, shfl stays pair-uniform
        if (jj + 1 < n) {
          float s2 = 0.f;
#pragma unroll
          for (int m = 0; m < 8; ++m) {
            s2 += qt[m]      * bf2f((unsigned short)Bk0[m]);
            s2 += qt[8 + m]  * bf2f((unsigned short)Bk1[m]);
            s2 += qt[16 + m] * bf2f((unsigned short)Bk2[m]);
            s2 += qt[24 + m] * bf2f((unsigned short)Bk3[m]);
          }
          s2 += __shfl_xor(s2, 32);
          float ex2 = __expf(s2 * prs);
          dtot += ex2;
#pragma unroll
          for (int m = 0; m < 8; ++m) {
            acc[m]      += ex2 * bf2f((unsigned short)Bv0[m]);
            acc[8 + m]  += ex2 * bf2f((unsigned short)Bv1[m]);
            acc[16 + m] += ex2 * bf2f((unsigned short)Bv2[m]);
            acc[24 + m] += ex2 * bf2f((unsigned short)Bv3[m]);
          }
        }
        // refill B for edge jj+3
        int sB2 = (jj + 3 < n) ? je[b0 + jj + 3] : 0;
        const unsigned short* nB = base_kv + (size_t)sB2 * 512;
        Bk0 = *(const bf16x8*)nB;        Bk1 = *(const bf16x8*)(nB + 8);
        Bk2 = *(const bf16x8*)(nB + 16); Bk3 = *(const bf16x8*)(nB + 24);
        Bv0 = *(const bf16x8*)(nB + 64); Bv1 = *(const bf16x8*)(nB + 72);
        Bv2 = *(const bf16x8*)(nB + 80); Bv3 = *(const bf16x8*)(nB + 88);
      }
    }
    // ---- phase 3: stage acc -> qsh (clobbers qt), M-transform via MFMA ----
#pragma unroll
    for (int m = 0; m < 32; m += 4) {
      f32x4 v = {acc[m], acc[m + 1], acc[m + 2], acc[m + 3]};
      *(f32x4*)&qsh[h][lr32][kq1 * 32 + m] = v;
    }
#pragma unroll
    for (int hf = 0; hf < 2; ++hf) {
      bf16x8 m0, m1;
#pragma unroll
      for (int m = 0; m < 8; ++m) {
        m0[m] = (short)f2bf(qsh[h][hf * 16 + lr16][kq4 * 8 + m]);
        m1[m] = (short)f2bf(qsh[h][hf * 16 + lr16][32 + kq4 * 8 + m]);
      }
#pragma unroll
      for (int tn = 0; tn < 4; ++tn) {
        const unsigned short* bp = Mt + ((rh * 64 + tn * 16 + lr16) * 64) + kq4 * 8;
        C[hf][tn] = mfma16(m0, *(const bf16x8*)bp, C[hf][tn]);
        C[hf][tn] = mfma16(m1, *(const bf16x8*)(bp + 32), C[hf][tn]);
      }
    }
  }
  if (kq1 == 0) atomicAdd(&denom[(dt * 32 + lr32) * 4 + h], dtot);
#pragma unroll
  for (int hf = 0; hf < 2; ++hf)
#pragma unroll
    for (int tn = 0; tn < 4; ++tn)
#pragma unroll
      for (int i = 0; i < 4; ++i)
        aggh[((size_t)quarter * NN + dt * 32 + hf * 16 + kq4 * 4 + i) * 256 +
             h * 64 + tn * 16 + lr16] = f2bf(C[hf][tn][i]);
}

// ---------------- K3: final projection, 64-row x 8-col-tile blocks ------------------
__global__ __launch_bounds__(256) void k_gemm_out(
    const unsigned short* __restrict__ aggh, const float* __restrict__ denom,
    const unsigned short* __restrict__ At,
    const int* __restrict__ nperm, const int* __restrict__ toff,
    const int* __restrict__ mt64_t, const int* __restrict__ mt64_m,
    const int* __restrict__ gcnt,
    const float* __restrict__ skip, float* __restrict__ out) {
  __shared__ unsigned short bs[16][264];
  int mtile = blockIdx.x >> 1, chunk = blockIdx.x & 1;
  if (mtile >= gcnt[0]) return;
  int wave = threadIdx.x >> 6, lane = threadIdx.x & 63;
  int t = mt64_t[mtile], tm = mt64_m[mtile];
  int base = toff[t], cnt = toff[t + 1] - base;
  int lr = lane & 15, kq = lane >> 4;
  int arow = tm * 64 + wave * 16 + lr;
  int prow = base + (arow < cnt ? arow : cnt - 1);
  float dn[4];
#pragma unroll
  for (int hh = 0; hh < 4; ++hh) {
    float d = denom[prow * 4 + hh];
    dn[hh] = d > 0.f ? 1.f / d : 0.f;
  }
  const unsigned short* g = aggh + (size_t)prow * 256 + kq * 8;
  bf16x8 af[8];
#pragma unroll
  for (int s = 0; s < 8; ++s) {
    bf16x8 x0 = *(const bf16x8*)(g + s * 32);
    bf16x8 x1 = *(const bf16x8*)(g + (size_t)NN * 256 + s * 32);
    bf16x8 x2 = *(const bf16x8*)(g + (size_t)2 * NN * 256 + s * 32);
    bf16x8 x3 = *(const bf16x8*)(g + (size_t)3 * NN * 256 + s * 32);
    float dv = dn[(kq * 8 + s * 32) >> 6];
#pragma unroll
    for (int m = 0; m < 8; ++m)
      af[s][m] = (short)f2bf((bf2f((unsigned short)x0[m]) + bf2f((unsigned short)x1[m]) +
                              bf2f((unsigned short)x2[m]) + bf2f((unsigned short)x3[m])) * dv);
  }
  int nd[4]; bool wr[4];
#pragma unroll
  for (int i = 0; i < 4; ++i) {
    int crow = tm * 64 + wave * 16 + kq * 4 + i;
    wr[i] = crow < cnt;
    nd[i] = nperm[base + (wr[i] ? crow : 0)];
  }
  float sg = 1.f / (1.f + __expf(-skip[t]));
  int sc = threadIdx.x >> 4;
  int seg = threadIdx.x & 15;
  for (int tt = 0; tt < 8; ++tt) {
    int tn = chunk * 8 + tt;
    const unsigned short* wsrc = At + ((size_t)(t * 256 + tn * 16 + sc)) * 256 + seg * 16;
    __syncthreads();
    *(bf16x8*)&bs[sc][seg * 16]     = *(const bf16x8*)wsrc;
    *(bf16x8*)&bs[sc][seg * 16 + 8] = *(const bf16x8*)(wsrc + 8);
    __syncthreads();
    f32x4 acc = {0.f, 0.f, 0.f, 0.f};
#pragma unroll
    for (int s = 0; s < 8; ++s)
      acc = mfma16(af[s], *(const bf16x8*)&bs[lr][kq * 8 + s * 32], acc);
    int ccol = tn * 16 + lr;
#pragma unroll
    for (int i = 0; i < 4; ++i)
      if (wr[i]) out[nd[i] * 256 + ccol] = acc[i] * sg;
  }
}

extern "C" void kernel_launch(void* const* d_in, const int* in_sizes, int n_in,
                              void* d_out, int out_size, void* d_ws, size_t ws_size,
                              hipStream_t stream) {
  (void)in_sizes; (void)n_in; (void)out_size; (void)ws_size;
  const float* h    = (const float*)d_in[0];
  const float* Wk   = (const float*)d_in[1];
  const float* Wq   = (const float*)d_in[2];
  const float* Wv   = (const float*)d_in[3];
  const float* Wa   = (const float*)d_in[4];
  const float* ratt = (const float*)d_in[5];
  const float* rmsg = (const float*)d_in[6];
  const float* pri  = (const float*)d_in[7];
  const float* skp  = (const float*)d_in[8];
  const int* ntype  = (const int*)d_in[9];
  const int* etyp   = (const int*)d_in[10];
  const int* rowi   = (const int*)d_in[11];
  const int* coli   = (const int*)d_in[12];
  float* out = (float*)d_out;

  char* p = (char*)d_ws;
  auto alloc = [&](size_t bytes) {
    void* q = (void*)p;
    p += (bytes + 255) & ~(size_t)255;
    return q;
  };
  unsigned short* Wt   = (unsigned short*)alloc((size_t)4 * 768 * 256 * 2);
  unsigned short* At   = (unsigned short*)alloc((size_t)4 * 256 * 256 * 2);
  unsigned short* Att  = (unsigned short*)alloc((size_t)32 * 4096 * 2);
  unsigned short* Mt   = (unsigned short*)alloc((size_t)32 * 4096 * 2);
  unsigned short* kvb  = (unsigned short*)alloc((size_t)NN * 512 * 2);
  unsigned short* qb   = (unsigned short*)alloc((size_t)NN * 256 * 2);
  unsigned short* aggh = (unsigned short*)alloc((size_t)4 * NN * 256 * 2);
  float* denom = (float*)alloc((size_t)NN * 4 * 4);
  int* toff   = (int*)alloc(32);
  int* ncur   = (int*)alloc(16);
  int* c4p    = (int*)alloc((size_t)CB * 4 * 4);
  int* nperm  = (int*)alloc((size_t)NN * 4);
  int* inv    = (int*)alloc((size_t)NN * 4);
  int* bcnt   = (int*)alloc((size_t)NB * 4);
  int* boff   = (int*)alloc((size_t)(NB + 1) * 4);
  int* bcur   = (int*)alloc((size_t)NB * 4);
  int* psum   = (int*)alloc((size_t)625 * 4);
  int* je     = (int*)alloc((size_t)NE * 4);
  int* mt64_t = (int*)alloc((size_t)324 * 4);
  int* mt64_m = (int*)alloc((size_t)324 * 4);
  int* gcnt   = (int*)alloc(32);

  // fused prep (zero + type-count + coalesced transposes)
  k_prep_all<<<ZB + CB + WSEG + ASEG + RSEG, 256, 0, stream>>>(
      Wk, Wq, Wv, Wa, ratt, rmsg, ntype, bcnt, denom, c4p, Wt, At, Att, Mt);
  k_meta<<<1, 256, 0, stream>>>(c4p, toff, ncur, mt64_t, mt64_m, gcnt);
  k_nscatter<<<CB, 256, 0, stream>>>(ntype, ncur, nperm, inv);

  // edge CSR by (rel, perm-dst)
  k_bcount<<<(NE + 255) / 256, 256, 0, stream>>>(etyp, coli, inv, bcnt);
  k_scan1<<<625, 256, 0, stream>>>(bcnt, boff, psum);
  k_scan2<<<1, 1024, 0, stream>>>(psum);
  k_scan3<<<625, 256, 0, stream>>>(boff, bcur, psum);
  k_escatter<<<(NE + 255) / 256, 256, 0, stream>>>(etyp, rowi, coli, inv, bcur, je);

  // main pipeline
  k_gemm_kqv<<<960, 256, 0, stream>>>(h, Wt, nperm, toff, mt64_t, mt64_m, gcnt, kvb, qb);
  k_mega<<<2500, 256, 0, stream>>>(boff, je, qb, kvb, Att, Mt, pri, aggh, denom);
  k_gemm_out<<<640, 256, 0, stream>>>(aggh, denom, At, nperm, toff, mt64_t, mt64_m, gcnt,
                                      skp, out);
}

// Round 17
// 329.070 us; speedup vs baseline: 1.0281x; 1.0281x over previous
//
#include <hip/hip_runtime.h>

static constexpr int NN  = 20000;
static constexpr int NE  = 320000;
static constexpr int NTY = 4;
static constexpr int NRL = 8;
static constexpr int NB  = NRL * NN;   // 160000 bins = (rel, perm-dst)

// prep-kernel segment sizes (blocks of 256)
static constexpr int ZB   = (NB + NN * 4 + 255) / 256;  // 938  (zero bcnt+denom)
static constexpr int CB   = (NN + 255) / 256;           // 79   (type-count blocks)
static constexpr int WSEG = 192;                        // 12 mats x 16 tiles (Wk/Wq/Wv)
static constexpr int ASEG = 64;                         // 4 mats x 16 tiles (Wa)
static constexpr int RSEG = 32;                         // 32 rh, att+msg each

typedef short bf16x8 __attribute__((ext_vector_type(8)));
typedef float f32x4  __attribute__((ext_vector_type(4)));
typedef unsigned short u16x4 __attribute__((ext_vector_type(4)));

__device__ __forceinline__ unsigned short f2bf(float f) {
  unsigned u = __float_as_uint(f);
  u += 0x7fffu + ((u >> 16) & 1u);
  return (unsigned short)(u >> 16);
}
__device__ __forceinline__ float bf2f(unsigned short b) {
  return __uint_as_float(((unsigned)b) << 16);
}
__device__ __forceinline__ f32x4 mfma16(bf16x8 a, bf16x8 b, f32x4 c) {
  return __builtin_amdgcn_mfma_f32_16x16x32_bf16(a, b, c, 0, 0, 0);
}

// ---------------- fused prep: zero + tcount + coalesced tiled transposes -----------
__global__ void k_prep_all(const float* __restrict__ Wk, const float* __restrict__ Wq,
                           const float* __restrict__ Wv, const float* __restrict__ Wa,
                           const float* __restrict__ ratt, const float* __restrict__ rmsg,
                           const int* __restrict__ ntype,
                           int* bcnt, float* denom, int* c4p,
                           unsigned short* Wt, unsigned short* At,
                           unsigned short* Att, unsigned short* Mt) {
  __shared__ float tl[64][65];
  __shared__ int cc[4];
  int b = blockIdx.x, tid = threadIdx.x;
  if (b < ZB) {
    int i = b * 256 + tid;
    if (i < NB) bcnt[i] = 0;
    else if (i < NB + NN * 4) denom[i - NB] = 0.f;
    return;
  }
  b -= ZB;
  if (b < CB) {
    if (tid < 4) cc[tid] = 0;
    __syncthreads();
    int i = b * 256 + tid;
    if (i < NN) atomicAdd(&cc[ntype[i]], 1);
    __syncthreads();
    if (tid < 4) c4p[b * 4 + tid] = cc[tid];
    return;
  }
  b -= CB;
  int r4 = tid >> 6, c = tid & 63;
  if (b < WSEG) {
    int mat = b >> 4, tile = b & 15;
    int t = mat / 3, w = mat % 3;
    const float* src = (w == 0) ? Wk : (w == 1) ? Wq : Wv;
    src += (size_t)t * 65536;
    int ti = (tile >> 2) * 64, tj = (tile & 3) * 64;
#pragma unroll
    for (int p = 0; p < 16; ++p) {
      int row = p * 4 + r4;
      tl[row][c] = src[(size_t)(ti + row) * 256 + tj + c];
    }
    __syncthreads();
#pragma unroll
    for (int p = 0; p < 16; ++p) {
      int jr = p * 4 + r4;
      Wt[((size_t)(t * 768 + w * 256 + tj + jr)) * 256 + ti + c] = f2bf(tl[c][jr]);
    }
    return;
  }
  b -= WSEG;
  if (b < ASEG) {
    int t = b >> 4, tile = b & 15;
    int ti = (tile >> 2) * 64, tj = (tile & 3) * 64;
#pragma unroll
    for (int p = 0; p < 16; ++p) {
      int row = p * 4 + r4;
      tl[row][c] = Wa[(size_t)(t * 256 + ti + row) * 256 + tj + c];
    }
    __syncthreads();
#pragma unroll
    for (int p = 0; p < 16; ++p) {
      int jr = p * 4 + r4;
      At[((size_t)(t * 256 + tj + jr)) * 256 + ti + c] = f2bf(tl[c][jr]);
    }
    return;
  }
  b -= ASEG;
  {
    int rh = b;  // 0..31
#pragma unroll
    for (int p = 0; p < 16; ++p) {
      int d = p * 4 + r4;
      tl[d][c] = ratt[(size_t)rh * 4096 + d * 64 + c];
    }
    __syncthreads();
#pragma unroll
    for (int p = 0; p < 16; ++p) {
      int e = p * 4 + r4;
      Att[(size_t)rh * 4096 + e * 64 + c] = f2bf(tl[c][e]);
    }
    __syncthreads();
#pragma unroll
    for (int p = 0; p < 16; ++p) {
      int d = p * 4 + r4;
      tl[d][c] = rmsg[(size_t)rh * 4096 + d * 64 + c];
    }
    __syncthreads();
#pragma unroll
    for (int p = 0; p < 16; ++p) {
      int e = p * 4 + r4;
      Mt[(size_t)rh * 4096 + e * 64 + c] = f2bf(tl[c][e]);
    }
  }
}

// meta: type offsets + 64-row tile list
__global__ void k_meta(const int* __restrict__ c4p, int* toff, int* ncur,
                       int* mt64_t, int* mt64_m, int* gcnt) {
  __shared__ int c4[4];
  __shared__ int ts[5];
  if (threadIdx.x < 4) {
    int s = 0;
    for (int b = 0; b < CB; ++b) s += c4p[b * 4 + threadIdx.x];
    c4[threadIdx.x] = s;
  }
  __syncthreads();
  if (threadIdx.x == 0) {
    int s = 0, s2 = 0;
    for (int t = 0; t < NTY; ++t) {
      toff[t] = s; ncur[t] = s; s += c4[t];
      ts[t] = s2; s2 += (c4[t] + 63) >> 6;
    }
    toff[NTY] = s; ts[NTY] = s2; gcnt[0] = s2;
  }
  __syncthreads();
  int n64 = ts[4];
  for (int i = threadIdx.x; i < n64; i += 256) {
    int t = 0;
    while (t < 3 && i >= ts[t + 1]) ++t;
    mt64_t[i] = t; mt64_m[i] = i - ts[t];
  }
}
__global__ void k_nscatter(const int* __restrict__ key, int* cur,
                           int* nperm, int* inv) {
  int i = blockIdx.x * 256 + threadIdx.x;
  if (i < NN) {
    int p = atomicAdd(&cur[key[i]], 1);
    nperm[p] = i;
    inv[i] = p;
  }
}

// ---------------- edge CSR by (rel, perm-dst) ----------------
__global__ void k_bcount(const int* __restrict__ etyp, const int* __restrict__ coli,
                         const int* __restrict__ inv, int* bcnt) {
  int e = blockIdx.x * 256 + threadIdx.x;
  if (e < NE) atomicAdd(&bcnt[etyp[e] * NN + inv[coli[e]]], 1);
}
__global__ void k_scan1(const int* cnt, int* off, int* psum) {
  __shared__ int sm[256];
  int i = blockIdx.x * 256 + threadIdx.x;
  int v = cnt[i];
  sm[threadIdx.x] = v;
  __syncthreads();
  for (int d = 1; d < 256; d <<= 1) {
    int t = (threadIdx.x >= d) ? sm[threadIdx.x - d] : 0;
    __syncthreads();
    sm[threadIdx.x] += t;
    __syncthreads();
  }
  off[i] = sm[threadIdx.x] - v;
  if (threadIdx.x == 255) psum[blockIdx.x] = sm[255];
}
__global__ void k_scan2(int* psum) {
  __shared__ int sm[1024];
  int t = threadIdx.x;
  int v = (t < 625) ? psum[t] : 0;
  sm[t] = v;
  __syncthreads();
  for (int d = 1; d < 1024; d <<= 1) {
    int x = (t >= d) ? sm[t - d] : 0;
    __syncthreads();
    sm[t] += x;
    __syncthreads();
  }
  if (t < 625) psum[t] = sm[t] - v;
}
__global__ void k_scan3(int* off, int* cur, const int* psum) {
  int i = blockIdx.x * 256 + threadIdx.x;
  int v = off[i] + psum[blockIdx.x];
  off[i] = v; cur[i] = v;
  if (i == 0) off[NB] = NE;
}
__global__ void k_escatter(const int* __restrict__ etyp, const int* __restrict__ rowi,
                           const int* __restrict__ coli, const int* __restrict__ inv,
                           int* cur, int* je) {
  int e = blockIdx.x * 256 + threadIdx.x;
  if (e >= NE) return;
  int bin = etyp[e] * NN + inv[coli[e]];
  int j = atomicAdd(&cur[bin], 1);
  je[j] = inv[rowi[e]];
}

// ---------------- K1: typed K/Q/V projection, 64-row x 16-col-tile blocks ------------
__global__ __launch_bounds__(256) void k_gemm_kqv(
    const float* __restrict__ hsrc, const unsigned short* __restrict__ Wt,
    const int* __restrict__ nperm, const int* __restrict__ toff,
    const int* __restrict__ mt64_t, const int* __restrict__ mt64_m,
    const int* __restrict__ gcnt,
    unsigned short* __restrict__ kvb, unsigned short* __restrict__ qb) {
  __shared__ unsigned short bs[16][264];
  int mtile = blockIdx.x / 3, chunk = blockIdx.x % 3;
  if (mtile >= gcnt[0]) return;
  int wave = threadIdx.x >> 6, lane = threadIdx.x & 63;
  int t = mt64_t[mtile], tm = mt64_m[mtile];
  int base = toff[t], cnt = toff[t + 1] - base;
  int lr = lane & 15, kq = lane >> 4;
  int arow = tm * 64 + wave * 16 + lr;
  int prow = base + (arow < cnt ? arow : cnt - 1);
  int node = nperm[prow];
  const float* ap = hsrc + (size_t)node * 256 + kq * 8;
  bf16x8 af[8];
#pragma unroll
  for (int s = 0; s < 8; ++s) {
    f32x4 x0 = *(const f32x4*)(ap + s * 32);
    f32x4 x1 = *(const f32x4*)(ap + s * 32 + 4);
    bf16x8 o;
    o[0] = (short)f2bf(x0[0]); o[1] = (short)f2bf(x0[1]);
    o[2] = (short)f2bf(x0[2]); o[3] = (short)f2bf(x0[3]);
    o[4] = (short)f2bf(x1[0]); o[5] = (short)f2bf(x1[1]);
    o[6] = (short)f2bf(x1[2]); o[7] = (short)f2bf(x1[3]);
    af[s] = o;
  }
  int pr[4]; bool wr[4];
#pragma unroll
  for (int i = 0; i < 4; ++i) {
    int crow = tm * 64 + wave * 16 + kq * 4 + i;
    wr[i] = crow < cnt;
    pr[i] = base + (wr[i] ? crow : 0);
  }
  int sc = threadIdx.x >> 4;     // staging col 0..15
  int seg = threadIdx.x & 15;    // staging 16-short segment
  for (int tt = 0; tt < 16; ++tt) {
    int tn = chunk * 16 + tt;
    const unsigned short* wsrc = Wt + ((size_t)(t * 768 + tn * 16 + sc)) * 256 + seg * 16;
    __syncthreads();
    *(bf16x8*)&bs[sc][seg * 16]     = *(const bf16x8*)wsrc;
    *(bf16x8*)&bs[sc][seg * 16 + 8] = *(const bf16x8*)(wsrc + 8);
    __syncthreads();
    f32x4 acc = {0.f, 0.f, 0.f, 0.f};
#pragma unroll
    for (int s = 0; s < 8; ++s)
      acc = mfma16(af[s], *(const bf16x8*)&bs[lr][kq * 8 + s * 32], acc);
    int ccol = tn * 16 + lr;
#pragma unroll
    for (int i = 0; i < 4; ++i) {
      if (wr[i]) {
        unsigned short v = f2bf(acc[i]);
        if (ccol < 256)
          kvb[(size_t)pr[i] * 512 + (ccol >> 6) * 128 + (ccol & 63)] = v;
        else if (ccol < 512)
          qb[(size_t)pr[i] * 256 + (ccol - 256)] = v;
        else {
          int c = ccol - 512;
          kvb[(size_t)pr[i] * 512 + (c >> 6) * 128 + 64 + (c & 63)] = v;
        }
      }
    }
  }
}

// ---------------- K2: mega — 32 bins/wave, f32 LDS + je prefetch + XCD swizzle ------
__global__ __launch_bounds__(256) void k_mega(
    const int* __restrict__ boff, const int* __restrict__ je,
    const unsigned short* __restrict__ qb, const unsigned short* __restrict__ kvb,
    const unsigned short* __restrict__ Att, const unsigned short* __restrict__ Mt,
    const float* __restrict__ pri, unsigned short* __restrict__ aggh,
    float* __restrict__ denom) {
  __shared__ float qsh[4][32][68];   // [head][dst_local][dim] f32, stride 68
  int xcd = blockIdx.x & 7, loc = blockIdx.x >> 3;
  int virt = (xcd < 4) ? xcd * 313 + loc : 1252 + (xcd - 4) * 312 + loc;
  int dt = virt >> 2, quarter = virt & 3;
  int h = threadIdx.x >> 6, lane = threadIdx.x & 63;
  int lr16 = lane & 15, kq4 = lane >> 4;    // MFMA mapping
  int lr32 = lane & 31, kq1 = lane >> 5;    // edge-loop mapping
  int r0 = quarter * 2;
  float dtot = 0.f;
  f32x4 C[2][4] = {{{0.f,0.f,0.f,0.f},{0.f,0.f,0.f,0.f},{0.f,0.f,0.f,0.f},{0.f,0.f,0.f,0.f}},
                   {{0.f,0.f,0.f,0.f},{0.f,0.f,0.f,0.f},{0.f,0.f,0.f,0.f},{0.f,0.f,0.f,0.f}}};
  for (int rr = 0; rr < 2; ++rr) {
    int r = r0 + rr;
    int rh = r * 4 + h;
    int bin = r * NN + dt * 32 + lr32;
    int b0 = boff[bin], b1 = boff[bin + 1];
    // ---- phase 1: qt = q @ A_r^T via MFMA (two 16-row halves) -> qsh f32 ----
#pragma unroll
    for (int hf = 0; hf < 2; ++hf) {
      const unsigned short* ap = qb + (size_t)(dt * 32 + hf * 16 + lr16) * 256 + h * 64 + kq4 * 8;
      bf16x8 aq0 = *(const bf16x8*)ap;
      bf16x8 aq1 = *(const bf16x8*)(ap + 32);
#pragma unroll
      for (int tn = 0; tn < 4; ++tn) {
        const unsigned short* bp = Att + ((rh * 64 + tn * 16 + lr16) * 64) + kq4 * 8;
        f32x4 a = {0.f, 0.f, 0.f, 0.f};
        a = mfma16(aq0, *(const bf16x8*)bp, a);
        a = mfma16(aq1, *(const bf16x8*)(bp + 32), a);
#pragma unroll
        for (int i = 0; i < 4; ++i)
          qsh[h][hf * 16 + kq4 * 4 + i][tn * 16 + lr16] = a[i];
      }
    }
    // ---- qt -> registers (wave-local LDS round trip) ----
    float qt[32];
#pragma unroll
    for (int m = 0; m < 32; m += 4) {
      f32x4 v = *(const f32x4*)&qsh[h][lr32][kq1 * 32 + m];
      qt[m] = v[0]; qt[m + 1] = v[1]; qt[m + 2] = v[2]; qt[m + 3] = v[3];
    }
    // ---- phase 2: per-lane bin walk with 1-deep je prefetch ----
    float acc[32];
#pragma unroll
    for (int m = 0; m < 32; ++m) acc[m] = 0.f;
    float prs = pri[rh] * 0.125f;
    int src_next = (b0 < b1) ? je[b0] : 0;
    for (int j = b0; j < b1; ++j) {
      int src = src_next;
      if (j + 1 < b1) src_next = je[j + 1];
      const unsigned short* kp = kvb + (size_t)src * 512 + h * 128 + kq1 * 32;
      bf16x8 k0 = *(const bf16x8*)kp;
      bf16x8 k1 = *(const bf16x8*)(kp + 8);
      bf16x8 k2 = *(const bf16x8*)(kp + 16);
      bf16x8 k3 = *(const bf16x8*)(kp + 24);
      bf16x8 v0 = *(const bf16x8*)(kp + 64);
      bf16x8 v1 = *(const bf16x8*)(kp + 72);
      bf16x8 v2 = *(const bf16x8*)(kp + 80);
      bf16x8 v3 = *(const bf16x8*)(kp + 88);
      float s = 0.f;
#pragma unroll
      for (int m = 0; m < 8; ++m) {
        s += qt[m]      * bf2f((unsigned short)k0[m]);
        s += qt[8 + m]  * bf2f((unsigned short)k1[m]);
        s += qt[16 + m] * bf2f((unsigned short)k2[m]);
        s += qt[24 + m] * bf2f((unsigned short)k3[m]);
      }
      s += __shfl_xor(s, 32);
      float ex = __expf(s * prs);
      dtot += ex;
#pragma unroll
      for (int m = 0; m < 8; ++m) {
        acc[m]      += ex * bf2f((unsigned short)v0[m]);
        acc[8 + m]  += ex * bf2f((unsigned short)v1[m]);
        acc[16 + m] += ex * bf2f((unsigned short)v2[m]);
        acc[24 + m] += ex * bf2f((unsigned short)v3[m]);
      }
    }
    // ---- phase 3: stage acc -> qsh (clobbers qt), M-transform via MFMA ----
#pragma unroll
    for (int m = 0; m < 32; m += 4) {
      f32x4 v = {acc[m], acc[m + 1], acc[m + 2], acc[m + 3]};
      *(f32x4*)&qsh[h][lr32][kq1 * 32 + m] = v;
    }
#pragma unroll
    for (int hf = 0; hf < 2; ++hf) {
      bf16x8 m0, m1;
#pragma unroll
      for (int m = 0; m < 8; ++m) {
        m0[m] = (short)f2bf(qsh[h][hf * 16 + lr16][kq4 * 8 + m]);
        m1[m] = (short)f2bf(qsh[h][hf * 16 + lr16][32 + kq4 * 8 + m]);
      }
#pragma unroll
      for (int tn = 0; tn < 4; ++tn) {
        const unsigned short* bp = Mt + ((rh * 64 + tn * 16 + lr16) * 64) + kq4 * 8;
        C[hf][tn] = mfma16(m0, *(const bf16x8*)bp, C[hf][tn]);
        C[hf][tn] = mfma16(m1, *(const bf16x8*)(bp + 32), C[hf][tn]);
      }
    }
  }
  if (kq1 == 0) atomicAdd(&denom[(dt * 32 + lr32) * 4 + h], dtot);
#pragma unroll
  for (int hf = 0; hf < 2; ++hf)
#pragma unroll
    for (int tn = 0; tn < 4; ++tn)
#pragma unroll
      for (int i = 0; i < 4; ++i)
        aggh[((size_t)quarter * NN + dt * 32 + hf * 16 + kq4 * 4 + i) * 256 +
             h * 64 + tn * 16 + lr16] = f2bf(C[hf][tn][i]);
}

// ---------------- K3: final projection, 64-row x 8-col-tile blocks ------------------
__global__ __launch_bounds__(256) void k_gemm_out(
    const unsigned short* __restrict__ aggh, const float* __restrict__ denom,
    const unsigned short* __restrict__ At,
    const int* __restrict__ nperm, const int* __restrict__ toff,
    const int* __restrict__ mt64_t, const int* __restrict__ mt64_m,
    const int* __restrict__ gcnt,
    const float* __restrict__ skip, float* __restrict__ out) {
  __shared__ unsigned short bs[16][264];
  int mtile = blockIdx.x >> 1, chunk = blockIdx.x & 1;
  if (mtile >= gcnt[0]) return;
  int wave = threadIdx.x >> 6, lane = threadIdx.x & 63;
  int t = mt64_t[mtile], tm = mt64_m[mtile];
  int base = toff[t], cnt = toff[t + 1] - base;
  int lr = lane & 15, kq = lane >> 4;
  int arow = tm * 64 + wave * 16 + lr;
  int prow = base + (arow < cnt ? arow : cnt - 1);
  float dn[4];
#pragma unroll
  for (int hh = 0; hh < 4; ++hh) {
    float d = denom[prow * 4 + hh];
    dn[hh] = d > 0.f ? 1.f / d : 0.f;
  }
  const unsigned short* g = aggh + (size_t)prow * 256 + kq * 8;
  bf16x8 af[8];
#pragma unroll
  for (int s = 0; s < 8; ++s) {
    bf16x8 x0 = *(const bf16x8*)(g + s * 32);
    bf16x8 x1 = *(const bf16x8*)(g + (size_t)NN * 256 + s * 32);
    bf16x8 x2 = *(const bf16x8*)(g + (size_t)2 * NN * 256 + s * 32);
    bf16x8 x3 = *(const bf16x8*)(g + (size_t)3 * NN * 256 + s * 32);
    float dv = dn[(kq * 8 + s * 32) >> 6];
#pragma unroll
    for (int m = 0; m < 8; ++m)
      af[s][m] = (short)f2bf((bf2f((unsigned short)x0[m]) + bf2f((unsigned short)x1[m]) +
                              bf2f((unsigned short)x2[m]) + bf2f((unsigned short)x3[m])) * dv);
  }
  int nd[4]; bool wr[4];
#pragma unroll
  for (int i = 0; i < 4; ++i) {
    int crow = tm * 64 + wave * 16 + kq * 4 + i;
    wr[i] = crow < cnt;
    nd[i] = nperm[base + (wr[i] ? crow : 0)];
  }
  float sg = 1.f / (1.f + __expf(-skip[t]));
  int sc = threadIdx.x >> 4;
  int seg = threadIdx.x & 15;
  for (int tt = 0; tt < 8; ++tt) {
    int tn = chunk * 8 + tt;
    const unsigned short* wsrc = At + ((size_t)(t * 256 + tn * 16 + sc)) * 256 + seg * 16;
    __syncthreads();
    *(bf16x8*)&bs[sc][seg * 16]     = *(const bf16x8*)wsrc;
    *(bf16x8*)&bs[sc][seg * 16 + 8] = *(const bf16x8*)(wsrc + 8);
    __syncthreads();
    f32x4 acc = {0.f, 0.f, 0.f, 0.f};
#pragma unroll
    for (int s = 0; s < 8; ++s)
      acc = mfma16(af[s], *(const bf16x8*)&bs[lr][kq * 8 + s * 32], acc);
    int ccol = tn * 16 + lr;
#pragma unroll
    for (int i = 0; i < 4; ++i)
      if (wr[i]) out[nd[i] * 256 + ccol] = acc[i] * sg;
  }
}

extern "C" void kernel_launch(void* const* d_in, const int* in_sizes, int n_in,
                              void* d_out, int out_size, void* d_ws, size_t ws_size,
                              hipStream_t stream) {
  (void)in_sizes; (void)n_in; (void)out_size; (void)ws_size;
  const float* h    = (const float*)d_in[0];
  const float* Wk   = (const float*)d_in[1];
  const float* Wq   = (const float*)d_in[2];
  const float* Wv   = (const float*)d_in[3];
  const float* Wa   = (const float*)d_in[4];
  const float* ratt = (const float*)d_in[5];
  const float* rmsg = (const float*)d_in[6];
  const float* pri  = (const float*)d_in[7];
  const float* skp  = (const float*)d_in[8];
  const int* ntype  = (const int*)d_in[9];
  const int* etyp   = (const int*)d_in[10];
  const int* rowi   = (const int*)d_in[11];
  const int* coli   = (const int*)d_in[12];
  float* out = (float*)d_out;

  char* p = (char*)d_ws;
  auto alloc = [&](size_t bytes) {
    void* q = (void*)p;
    p += (bytes + 255) & ~(size_t)255;
    return q;
  };
  unsigned short* Wt   = (unsigned short*)alloc((size_t)4 * 768 * 256 * 2);
  unsigned short* At   = (unsigned short*)alloc((size_t)4 * 256 * 256 * 2);
  unsigned short* Att  = (unsigned short*)alloc((size_t)32 * 4096 * 2);
  unsigned short* Mt   = (unsigned short*)alloc((size_t)32 * 4096 * 2);
  unsigned short* kvb  = (unsigned short*)alloc((size_t)NN * 512 * 2);
  unsigned short* qb   = (unsigned short*)alloc((size_t)NN * 256 * 2);
  unsigned short* aggh = (unsigned short*)alloc((size_t)4 * NN * 256 * 2);
  float* denom = (float*)alloc((size_t)NN * 4 * 4);
  int* toff   = (int*)alloc(32);
  int* ncur   = (int*)alloc(16);
  int* c4p    = (int*)alloc((size_t)CB * 4 * 4);
  int* nperm  = (int*)alloc((size_t)NN * 4);
  int* inv    = (int*)alloc((size_t)NN * 4);
  int* bcnt   = (int*)alloc((size_t)NB * 4);
  int* boff   = (int*)alloc((size_t)(NB + 1) * 4);
  int* bcur   = (int*)alloc((size_t)NB * 4);
  int* psum   = (int*)alloc((size_t)625 * 4);
  int* je     = (int*)alloc((size_t)NE * 4);
  int* mt64_t = (int*)alloc((size_t)324 * 4);
  int* mt64_m = (int*)alloc((size_t)324 * 4);
  int* gcnt   = (int*)alloc(32);

  // fused prep (zero + type-count + coalesced transposes)
  k_prep_all<<<ZB + CB + WSEG + ASEG + RSEG, 256, 0, stream>>>(
      Wk, Wq, Wv, Wa, ratt, rmsg, ntype, bcnt, denom, c4p, Wt, At, Att, Mt);
  k_meta<<<1, 256, 0, stream>>>(c4p, toff, ncur, mt64_t, mt64_m, gcnt);
  k_nscatter<<<CB, 256, 0, stream>>>(ntype, ncur, nperm, inv);

  // edge CSR by (rel, perm-dst)
  k_bcount<<<(NE + 255) / 256, 256, 0, stream>>>(etyp, coli, inv, bcnt);
  k_scan1<<<625, 256, 0, stream>>>(bcnt, boff, psum);
  k_scan2<<<1, 1024, 0, stream>>>(psum);
  k_scan3<<<625, 256, 0, stream>>>(boff, bcur, psum);
  k_escatter<<<(NE + 255) / 256, 256, 0, stream>>>(etyp, rowi, coli, inv, bcur, je);

  // main pipeline
  k_gemm_kqv<<<960, 256, 0, stream>>>(h, Wt, nperm, toff, mt64_t, mt64_m, gcnt, kvb, qb);
  k_mega<<<2500, 256, 0, stream>>>(boff, je, qb, kvb, Att, Mt, pri, aggh, denom);
  k_gemm_out<<<640, 256, 0, stream>>>(aggh, denom, At, nperm, toff, mt64_t, mt64_m, gcnt,
                                      skp, out);
}